// Round 6
// baseline (1486.837 us; speedup 1.0000x reference)
//
#include <hip/hip_runtime.h>
#include <math.h>
#include <stdint.h>

typedef __bf16 bf16;
typedef __bf16 bf16x8 __attribute__((ext_vector_type(8)));
typedef __bf16 bf16x4 __attribute__((ext_vector_type(4)));
typedef float  f32x4  __attribute__((ext_vector_type(4)));

#define MFMA(a,b,c) __builtin_amdgcn_mfma_f32_16x16x32_bf16(a,b,c,0,0,0)

// fast erf, Abramowitz-Stegun 7.1.26, |err| <= 1.5e-7 (way below bf16 ulp)
__device__ __forceinline__ float erf_fast(float x){
    float ax = fabsf(x);
    float t = 1.0f / (1.0f + 0.3275911f * ax);
    float p = t*(0.254829592f + t*(-0.284496736f + t*(1.421413741f +
              t*(-1.453152027f + t*1.061405429f))));
    float r = 1.0f - p * __expf(-ax*ax);
    return copysignf(r, x);
}
__device__ __forceinline__ float gelu_exact(float z){
    return 0.5f * z * (1.0f + erf_fast(z * 0.70710678118654752f));
}

// async global->LDS, 16B per lane; LDS dest = wave-uniform base + lane*16
__device__ __forceinline__ void gload16(const void* g, void* l){
    __builtin_amdgcn_global_load_lds(
        (const __attribute__((address_space(1))) uint32_t*)(uintptr_t)g,
        (__attribute__((address_space(3))) uint32_t*)(uintptr_t)l,
        16, 0, 0);
}

// ---------------- weight prep: fp32 [K,N] -> bf16 [N,K] --------------------
__global__ void wprep(const float* __restrict__ W, bf16* __restrict__ WT, int K, int N)
{
    __shared__ float tile[32][33];
    int tx = threadIdx.x, ty = threadIdx.y;
    int n0 = blockIdx.x * 32, k0 = blockIdx.y * 32;
    for (int j = 0; j < 4; j++)
        tile[ty + j*8][tx] = W[(size_t)(k0 + ty + j*8) * N + n0 + tx];
    __syncthreads();
    for (int j = 0; j < 4; j++)
        WT[(size_t)(n0 + ty + j*8) * K + k0 + tx] = (bf16)tile[tx][ty + j*8];
}

// ---------------- bias concat for fused QKV --------------------------------
__global__ void bcat(const float* __restrict__ a, const float* __restrict__ b,
                     const float* __restrict__ c, float* __restrict__ o)
{
    int t = blockIdx.x * 256 + threadIdx.x;  // 3072 total
    o[t] = t < 1024 ? a[t] : (t < 2048 ? b[t - 1024] : c[t - 2048]);
}

// ---------------- LayerNorm (+ optional window-partition permute) ----------
template<int PERM>
__global__ __launch_bounds__(256) void ln_kernel(const float* __restrict__ x,
    const float* __restrict__ g, const float* __restrict__ beta,
    bf16* __restrict__ out)
{
    int rw = blockIdx.x;
    int src = rw;
    if (PERM){
        int w = rw >> 8, p = rw & 255;
        int b = w >> 4, inh = (w >> 2) & 3, inw = w & 3, pi = p >> 4, pj = p & 15;
        src = b * 4096 + (inh*16 + pi) * 64 + inw*16 + pj;
    }
    const float* xr = x + (size_t)src * 1024;
    int t = threadIdx.x;
    float4 xv = ((const float4*)xr)[t];
    float s  = xv.x + xv.y + xv.z + xv.w;
    float sq = xv.x*xv.x + xv.y*xv.y + xv.z*xv.z + xv.w*xv.w;
    for (int m = 1; m < 64; m <<= 1){ s += __shfl_xor(s, m); sq += __shfl_xor(sq, m); }
    __shared__ float red[8];
    int wid = t >> 6, lane = t & 63;
    if (lane == 0){ red[wid] = s; red[4 + wid] = sq; }
    __syncthreads();
    float S  = red[0] + red[1] + red[2] + red[3];
    float SQ = red[4] + red[5] + red[6] + red[7];
    float mean = S * (1.f/1024.f);
    float var  = SQ * (1.f/1024.f) - mean*mean;     // jnp.var: biased
    float rstd = rsqrtf(var + 1e-5f);
    float4 gv = ((const float4*)g)[t];
    float4 bv = ((const float4*)beta)[t];
    bf16x4 o;
    o[0] = (bf16)((xv.x - mean) * rstd * gv.x + bv.x);
    o[1] = (bf16)((xv.y - mean) * rstd * gv.y + bv.y);
    o[2] = (bf16)((xv.z - mean) * rstd * gv.z + bv.z);
    o[3] = (bf16)((xv.w - mean) * rstd * gv.w + bv.w);
    *(bf16x4*)(out + (size_t)rw * 1024 + t*4) = o;
}

// ---------------- 256x256 bf16 GEMM, register-pipelined 2-barrier ----------
// C[M,N] = epi(A[M,K] @ BT[N,K]^T + bias)
// EPI 0: bf16 out, +bias            (fused QKV)
// EPI 1: bf16 out, +bias, GELU      (MLP1)
// EPI 2: f32 out, +bias, +res, un-permute rows (O-proj -> x2)
// EPI 3: f32 out, +bias, +res       (MLP2 -> d_out)
//
// LDS 128 KiB dynamic: buf[2] x { B-lo | B-hi | A-lo | A-hi } x 16 KiB.
// Half-tile = 128 rows x 64 cols bf16, 16B chunks XOR-swizzled by (row&7).
// This is the ROUND-4 VERIFIED schedule (stage order B-lo,B-hi,A-lo,A-hi;
// gate lgkmcnt(0)+vmcnt(4) mid-tile; lgkmcnt(0) end-of-tile) with the two
// correctness-neutral barriers (old P0-end, P2-end) removed: the fused
// half-tiles touch disjoint LDS regions (B-lo/B-hi writes vs A reads;
// A-lo/A-hi writes vs buf[nxt] reads), so all cross-wave visibility is
// carried by the two remaining drain-then-barrier points:
//  - H0-end: lgkmcnt(0) [a1(j) reads retire before H1's A-restage] +
//    vmcnt(4) [4 newest = B(j+2) staged this tile; all older = tile j+1
//    fully landed] -> after barrier, H1 reads of buf[nxt] are safe.
//    Tail (j+2>=KT): vmcnt(0).
//  - H1-end: lgkmcnt(0) [a0/b(j+1) reads retire before H0(j+1)'s B-lo
//    restage and H1(j+1)'s A restages of the same buffer].
// Register liveness identical to round 4 (124 VGPR, no spill -> vmcnt
// arithmetic remains valid; b(j+1) reads stay AFTER the a1*b1[2,3] MFMA
// cluster because they overwrite b1).
template<int EPI>
__global__ __launch_bounds__(512, 2) void gemm256(
    const bf16* __restrict__ Ag, const bf16* __restrict__ BT,
    const float* __restrict__ bias, const float* __restrict__ res,
    void* __restrict__ outp, int N, int K)
{
    extern __shared__ char lds[];
    const int KT = K >> 6;
    const int gx = N >> 8;
    int nwg = gridDim.x;
    int id  = blockIdx.x;
    int cpx = nwg >> 3;                       // nwg % 8 == 0 for all our calls
    int wg  = (id & 7) * cpx + (id >> 3);     // XCD-aware swizzle (T1)
    int bx = wg % gx, by = wg / gx;
    int m0 = by << 8, n0 = bx << 8;

    int t = threadIdx.x;
    int lane = t & 63, wid = t >> 6;
    int wm = wid >> 2, wn = wid & 3;          // 2 x 4 wave grid
    int qoff = lane & 15, quad = lane >> 4;

    auto stage = [&](int kt, int h){          // h: 0=B-lo 1=B-hi 2=A-lo 3=A-hi
        int isA = h >> 1, hh = h & 1;
        char* lb = lds + ((kt & 1) << 16) + (isA << 15) + (hh << 14);
        const bf16* g0 = (isA ? Ag + (size_t)(m0 + (hh << 7)) * K
                              : BT + (size_t)(n0 + (hh << 7)) * K) + (kt << 6);
        #pragma unroll
        for (int ld = 0; ld < 2; ld++){
            int ch  = ld*512 + t;
            int row = ch >> 3;
            int cc  = (ch & 7) ^ (row & 7);   // pre-swizzled global source
            gload16(g0 + (size_t)row * K + cc*8, lb + (ld*512 + wid*64)*16);
        }
    };

    f32x4 acc[8][4] = {};
    bf16x8 a0[8], a1[8], b0[4], b1[4];

    const char* lA0 = lds + 32768 + (wm << 14) + qoff*128;
    const char* lB0 = lds + ((wn >> 1) << 14) + ((wn & 1) << 13) + qoff*128;
    int p0 = (quad ^ (qoff & 7)) << 4;
    int p1 = p0 ^ 64;

    // prologue: stage tiles 0 and 1 fully; read tile0 a0/b0/b1
    for (int kt = 0; kt < 2; ++kt)
        for (int h = 0; h < 4; ++h) stage(kt, h);
    asm volatile("s_waitcnt vmcnt(8)" ::: "memory");   // tile 0 staged (drain-then-barrier)
    __builtin_amdgcn_s_barrier();
    #pragma unroll
    for (int mt = 0; mt < 8; mt++) a0[mt] = *(const bf16x8*)(lA0 + mt*2048 + p0);
    #pragma unroll
    for (int nt = 0; nt < 4; nt++){
        b0[nt] = *(const bf16x8*)(lB0 + nt*2048 + p0);
        b1[nt] = *(const bf16x8*)(lB0 + nt*2048 + p1);
    }
    asm volatile("s_waitcnt lgkmcnt(0)" ::: "memory"); // drain before B-lo restage
    __builtin_amdgcn_s_barrier();

    for (int j = 0; j < KT; ++j){
        int cur = (j & 1) << 16;
        int nxt = cur ^ 0x10000;
        const char* lA  = lA0 + cur;
        const char* lAn = lA0 + nxt;
        const char* lBn = lB0 + nxt;
        bool sg = (j + 2 < KT);
        bool rd = (j + 1 < KT);

        // ---- H0: stage B-lo/B-hi(j+2); read a1(j); MFMA a0 x b0; gate; barrier
        if (sg) stage(j+2, 0);
        #pragma unroll
        for (int mt = 0; mt < 8; mt++)
            a1[mt] = *(const bf16x8*)(lA + mt*2048 + p1);
        __builtin_amdgcn_sched_barrier(0);
        __builtin_amdgcn_s_setprio(1);
        #pragma unroll
        for (int mt = 0; mt < 8; mt++){
            acc[mt][0] = MFMA(a0[mt], b0[0], acc[mt][0]);
            acc[mt][1] = MFMA(a0[mt], b0[1], acc[mt][1]);
        }
        __builtin_amdgcn_s_setprio(0);
        __builtin_amdgcn_sched_barrier(0);
        if (sg) stage(j+2, 1);
        __builtin_amdgcn_sched_barrier(0);
        __builtin_amdgcn_s_setprio(1);
        #pragma unroll
        for (int mt = 0; mt < 8; mt++){
            acc[mt][2] = MFMA(a0[mt], b0[2], acc[mt][2]);
            acc[mt][3] = MFMA(a0[mt], b0[3], acc[mt][3]);
        }
        __builtin_amdgcn_s_setprio(0);
        __builtin_amdgcn_sched_barrier(0);
        if (sg) asm volatile("s_waitcnt lgkmcnt(0) vmcnt(4)" ::: "memory");
        else    asm volatile("s_waitcnt lgkmcnt(0) vmcnt(0)" ::: "memory");
        __builtin_amdgcn_sched_barrier(0);
        __builtin_amdgcn_s_barrier();

        // ---- H1: stage A-lo/A-hi(j+2); read a0(j+1); MFMA a1 x b1;
        //          read b(j+1) AFTER b1's last use; drain; barrier
        if (sg) stage(j+2, 2);
        if (rd){
            #pragma unroll
            for (int mt = 0; mt < 8; mt++)
                a0[mt] = *(const bf16x8*)(lAn + mt*2048 + p0);
        }
        __builtin_amdgcn_sched_barrier(0);
        __builtin_amdgcn_s_setprio(1);
        #pragma unroll
        for (int mt = 0; mt < 8; mt++){
            acc[mt][0] = MFMA(a1[mt], b1[0], acc[mt][0]);
            acc[mt][1] = MFMA(a1[mt], b1[1], acc[mt][1]);
        }
        __builtin_amdgcn_s_setprio(0);
        __builtin_amdgcn_sched_barrier(0);
        if (sg) stage(j+2, 3);
        __builtin_amdgcn_sched_barrier(0);
        __builtin_amdgcn_s_setprio(1);
        #pragma unroll
        for (int mt = 0; mt < 8; mt++){
            acc[mt][2] = MFMA(a1[mt], b1[2], acc[mt][2]);
            acc[mt][3] = MFMA(a1[mt], b1[3], acc[mt][3]);
        }
        __builtin_amdgcn_s_setprio(0);
        __builtin_amdgcn_sched_barrier(0);
        if (rd){
            #pragma unroll
            for (int nt = 0; nt < 4; nt++){
                b0[nt] = *(const bf16x8*)(lBn + nt*2048 + p0);
                b1[nt] = *(const bf16x8*)(lBn + nt*2048 + p1);
            }
            asm volatile("s_waitcnt lgkmcnt(0)" ::: "memory");
        }
        __builtin_amdgcn_s_barrier();
    }

    // epilogue: C/D layout col=lane&15, row=quad*4+reg  [m91-verified]
    #pragma unroll
    for (int mt = 0; mt < 8; mt++){
        #pragma unroll
        for (int reg = 0; reg < 4; reg++){
            int grow = m0 + wm*128 + mt*16 + quad*4 + reg;
            size_t orow = (size_t)grow;
            if (EPI == 2){
                int w = grow >> 8, p = grow & 255;
                int b = w >> 4, inh = (w >> 2) & 3, inw = w & 3, pi = p >> 4, pj = p & 15;
                orow = (size_t)b * 4096 + (inh*16 + pi) * 64 + inw*16 + pj;
            }
            #pragma unroll
            for (int nt = 0; nt < 4; nt++){
                int gcol = n0 + wn*64 + nt*16 + qoff;
                float vv = acc[mt][nt][reg] + bias[gcol];
                if (EPI == 1) vv = gelu_exact(vv);
                if (EPI >= 2) vv += res[orow * (size_t)N + gcol];
                if (EPI <= 1) ((bf16*)outp)[orow * (size_t)N + gcol] = (bf16)vv;
                else          ((float*)outp)[orow * (size_t)N + gcol] = vv;
            }
        }
    }
}

// ---------------- windowed attention: 1 block per (window, head) -----------
// fused qkv layout: [32768 rows = win*256+pos][3072 = part*1024 + head*64+d]
__global__ __launch_bounds__(256) void attn_kernel(
    const bf16* __restrict__ qkv, bf16* __restrict__ ao)
{
    __shared__ bf16 VT[64 * 264];      // V^T: [d][kk], stride 264 (16B-aligned)
    __shared__ bf16 Pw[4][16 * 136];   // per-wave P scratch, stride 136
    int wh = blockIdx.x;
    int win = wh >> 4, head = wh & 15;
    size_t base = (size_t)win * 256;
    int cb = head * 64;
    int t = threadIdx.x, lane = t & 63, wv = t >> 6;
    int qoff = lane & 15, quad = lane >> 4;

    // stage V transposed
    const bf16* vb = qkv + base * 3072 + 2048 + cb;
    for (int i = 0; i < 8; i++){
        int c = t + i*256;
        int row = c >> 3, d0 = (c & 7) * 8;
        bf16x8 vvec = *(const bf16x8*)&vb[(size_t)row * 3072 + d0];
        for (int j = 0; j < 8; j++) VT[(d0 + j) * 264 + row] = vvec[j];
    }
    __syncthreads();

    const bf16* qb = qkv + base * 3072 + cb;
    const bf16* kb = qkv + base * 3072 + 1024 + cb;

    for (int qblk = 0; qblk < 4; qblk++){
        int m0 = wv * 64 + qblk * 16;
        bf16x8 aq0 = *(const bf16x8*)&qb[(size_t)(m0 + qoff) * 3072 + quad*8];
        bf16x8 aq1 = *(const bf16x8*)&qb[(size_t)(m0 + qoff) * 3072 + 32 + quad*8];
        f32x4 S[16];
        __builtin_amdgcn_s_setprio(1);
        for (int nt = 0; nt < 16; nt++){
            bf16x8 b0 = *(const bf16x8*)&kb[(size_t)(nt*16 + qoff) * 3072 + quad*8];
            bf16x8 b1 = *(const bf16x8*)&kb[(size_t)(nt*16 + qoff) * 3072 + 32 + quad*8];
            f32x4 a = {0.f, 0.f, 0.f, 0.f};
            a = MFMA(aq0, b0, a);
            a = MFMA(aq1, b1, a);
            S[nt] = a;
        }
        __builtin_amdgcn_s_setprio(0);
        // softmax over 256 keys; row = quad*4+reg, cols nt*16+qoff across 16 lanes
        float inv[4];
        for (int r = 0; r < 4; r++){
            float mx = -1e30f;
            for (int nt = 0; nt < 16; nt++) mx = fmaxf(mx, S[nt][r]);
            for (int m = 1; m < 16; m <<= 1) mx = fmaxf(mx, __shfl_xor(mx, m));
            float sum = 0.f;
            for (int nt = 0; nt < 16; nt++){
                float p = __expf((S[nt][r] - mx) * 0.125f);  // SCALE = 1/8
                S[nt][r] = p; sum += p;
            }
            for (int m = 1; m < 16; m <<= 1) sum += __shfl_xor(sum, m);
            inv[r] = 1.f / sum;
        }
        // PV in two k-halves through per-wave LDS (C-layout -> A-layout)
        f32x4 O[4] = {};
        for (int h = 0; h < 2; h++){
            for (int nt = 0; nt < 8; nt++)
                for (int r = 0; r < 4; r++)
                    Pw[wv][(quad*4 + r)*136 + nt*16 + qoff] = (bf16)S[h*8 + nt][r];
            __builtin_amdgcn_s_setprio(1);
            for (int ks = 0; ks < 4; ks++){
                bf16x8 ap = *(bf16x8*)&Pw[wv][qoff*136 + ks*32 + quad*8];
                for (int vt = 0; vt < 4; vt++){
                    bf16x8 bvv = *(bf16x8*)&VT[(vt*16 + qoff)*264 + (h*4 + ks)*32 + quad*8];
                    O[vt] = MFMA(ap, bvv, O[vt]);
                }
            }
            __builtin_amdgcn_s_setprio(0);
        }
        for (int vt = 0; vt < 4; vt++)
            for (int r = 0; r < 4; r++){
                size_t row = base + m0 + quad*4 + r;
                ao[row * 1024 + cb + vt*16 + qoff] = (bf16)(O[vt][r] * inv[r]);
            }
    }
}

// ---------------- orchestration -------------------------------------------
extern "C" void kernel_launch(void* const* d_in, const int* in_sizes, int n_in,
                              void* d_out, int out_size, void* d_ws, size_t ws_size,
                              hipStream_t stream)
{
    const float* x     = (const float*)d_in[0];
    const float* g1    = (const float*)d_in[1];
    const float* beta1 = (const float*)d_in[2];
    const float* Wq    = (const float*)d_in[3];
    const float* bq    = (const float*)d_in[4];
    const float* Wk    = (const float*)d_in[5];
    const float* bk    = (const float*)d_in[6];
    const float* Wv    = (const float*)d_in[7];
    const float* bv    = (const float*)d_in[8];
    const float* Wo    = (const float*)d_in[9];
    const float* bo    = (const float*)d_in[10];
    const float* g2    = (const float*)d_in[11];
    const float* beta2 = (const float*)d_in[12];
    const float* W1    = (const float*)d_in[13];
    const float* b1m   = (const float*)d_in[14];
    const float* W2    = (const float*)d_in[15];
    const float* b2m   = (const float*)d_in[16];

    char* ws = (char*)d_ws;
    const size_t MB = 1024ull * 1024ull;
    bf16* WqkvT = (bf16*)(ws + 0*MB);    // 6 MB  [3072][1024]
    bf16* WoT   = (bf16*)(ws + 6*MB);    // 2 MB
    bf16* W1T   = (bf16*)(ws + 8*MB);    // 8 MB  [4096][1024]
    bf16* W2T   = (bf16*)(ws + 16*MB);   // 8 MB  [1024][4096]
    bf16* hw    = (bf16*)(ws + 24*MB);   // 64 MB  (window-layout LN1 out)
    bf16* qkv   = (bf16*)(ws + 88*MB);   // 192 MB (fused q|k|v, stride 3072)
    bf16* ao    = (bf16*)(ws + 24*MB);   // reuse hw (consumed by QKV gemm)
    bf16* m1    = (bf16*)(ws + 24*MB);   // 256 MB overlay (hw+qkv, both dead)
    float* x2   = (float*)(ws + 280*MB); // 128 MB
    float* bqkv = (float*)(ws + 280*MB); // 12 KB, overlays x2 (dead until O-proj)
    bf16* h2    = (bf16*)(ws + 408*MB);  // 64 MB   -> total 472 MB

    static bool s_attr = false;
    if (!s_attr){
        s_attr = true;
        hipFuncSetAttribute(reinterpret_cast<const void*>(gemm256<0>),
                            hipFuncAttributeMaxDynamicSharedMemorySize, 131072);
        hipFuncSetAttribute(reinterpret_cast<const void*>(gemm256<1>),
                            hipFuncAttributeMaxDynamicSharedMemorySize, 131072);
        hipFuncSetAttribute(reinterpret_cast<const void*>(gemm256<2>),
                            hipFuncAttributeMaxDynamicSharedMemorySize, 131072);
        hipFuncSetAttribute(reinterpret_cast<const void*>(gemm256<3>),
                            hipFuncAttributeMaxDynamicSharedMemorySize, 131072);
    }

    dim3 tb(32, 8);

    // weight prep (Wq/Wk/Wv concatenated row-wise into WqkvT)
    wprep<<<dim3(32, 32),  tb, 0, stream>>>(Wq, WqkvT,              1024, 1024);
    wprep<<<dim3(32, 32),  tb, 0, stream>>>(Wk, WqkvT + 1024*1024,  1024, 1024);
    wprep<<<dim3(32, 32),  tb, 0, stream>>>(Wv, WqkvT + 2048*1024,  1024, 1024);
    wprep<<<dim3(32, 32),  tb, 0, stream>>>(Wo, WoT, 1024, 1024);
    wprep<<<dim3(128, 32), tb, 0, stream>>>(W1, W1T, 1024, 4096);
    wprep<<<dim3(32, 128), tb, 0, stream>>>(W2, W2T, 4096, 1024);
    bcat<<<12, 256, 0, stream>>>(bq, bk, bv, bqkv);

    // LN1 + window partition
    ln_kernel<1><<<32768, 256, 0, stream>>>(x, g1, beta1, hw);

    // fused QKV projection: [32768,1024] x [1024,3072]
    gemm256<0><<<12*128, 512, 131072, stream>>>(hw, WqkvT, bqkv, nullptr, qkv, 3072, 1024);

    // windowed attention (128 windows x 16 heads)
    attn_kernel<<<2048, 256, 0, stream>>>(qkv, ao);

    // O projection + bias + residual + window un-partition -> x2 (fp32)
    gemm256<2><<<4*128, 512, 131072, stream>>>(ao, WoT, bo, x, x2, 1024, 1024);

    // LN2
    ln_kernel<0><<<32768, 256, 0, stream>>>(x2, g2, beta2, h2);

    // MLP
    gemm256<1><<<16*128, 512, 131072, stream>>>(h2, W1T, b1m, nullptr, m1, 4096, 1024);
    gemm256<3><<<4*128, 512, 131072, stream>>>(m1, W2T, b2m, x2, (float*)d_out, 1024, 4096);
}

// Round 7
// 1438.072 us; speedup vs baseline: 1.0339x; 1.0339x over previous
//
#include <hip/hip_runtime.h>
#include <math.h>
#include <stdint.h>

typedef __bf16 bf16;
typedef __bf16 bf16x8 __attribute__((ext_vector_type(8)));
typedef __bf16 bf16x4 __attribute__((ext_vector_type(4)));
typedef float  f32x4  __attribute__((ext_vector_type(4)));

#define MFMA(a,b,c) __builtin_amdgcn_mfma_f32_16x16x32_bf16(a,b,c,0,0,0)

// fast erf, Abramowitz-Stegun 7.1.26, |err| <= 1.5e-7 (way below bf16 ulp)
__device__ __forceinline__ float erf_fast(float x){
    float ax = fabsf(x);
    float t = 1.0f / (1.0f + 0.3275911f * ax);
    float p = t*(0.254829592f + t*(-0.284496736f + t*(1.421413741f +
              t*(-1.453152027f + t*1.061405429f))));
    float r = 1.0f - p * __expf(-ax*ax);
    return copysignf(r, x);
}
__device__ __forceinline__ float gelu_exact(float z){
    return 0.5f * z * (1.0f + erf_fast(z * 0.70710678118654752f));
}

// async global->LDS, 16B per lane; LDS dest = wave-uniform base + lane*16
__device__ __forceinline__ void gload16(const void* g, void* l){
    __builtin_amdgcn_global_load_lds(
        (const __attribute__((address_space(1))) uint32_t*)(uintptr_t)g,
        (__attribute__((address_space(3))) uint32_t*)(uintptr_t)l,
        16, 0, 0);
}

// ---------------- weight prep: fp32 [K,N] -> bf16 [N,K] --------------------
__global__ void wprep(const float* __restrict__ W, bf16* __restrict__ WT, int K, int N)
{
    __shared__ float tile[32][33];
    int tx = threadIdx.x, ty = threadIdx.y;
    int n0 = blockIdx.x * 32, k0 = blockIdx.y * 32;
    for (int j = 0; j < 4; j++)
        tile[ty + j*8][tx] = W[(size_t)(k0 + ty + j*8) * N + n0 + tx];
    __syncthreads();
    for (int j = 0; j < 4; j++)
        WT[(size_t)(n0 + ty + j*8) * K + k0 + tx] = (bf16)tile[tx][ty + j*8];
}

// ---------------- bias concat for fused QKV --------------------------------
__global__ void bcat(const float* __restrict__ a, const float* __restrict__ b,
                     const float* __restrict__ c, float* __restrict__ o)
{
    int t = blockIdx.x * 256 + threadIdx.x;  // 3072 total
    o[t] = t < 1024 ? a[t] : (t < 2048 ? b[t - 1024] : c[t - 2048]);
}

// ---------------- LayerNorm (+ optional window-partition permute) ----------
template<int PERM>
__global__ __launch_bounds__(256) void ln_kernel(const float* __restrict__ x,
    const float* __restrict__ g, const float* __restrict__ beta,
    bf16* __restrict__ out)
{
    int rw = blockIdx.x;
    int src = rw;
    if (PERM){
        int w = rw >> 8, p = rw & 255;
        int b = w >> 4, inh = (w >> 2) & 3, inw = w & 3, pi = p >> 4, pj = p & 15;
        src = b * 4096 + (inh*16 + pi) * 64 + inw*16 + pj;
    }
    const float* xr = x + (size_t)src * 1024;
    int t = threadIdx.x;
    float4 xv = ((const float4*)xr)[t];
    float s  = xv.x + xv.y + xv.z + xv.w;
    float sq = xv.x*xv.x + xv.y*xv.y + xv.z*xv.z + xv.w*xv.w;
    for (int m = 1; m < 64; m <<= 1){ s += __shfl_xor(s, m); sq += __shfl_xor(sq, m); }
    __shared__ float red[8];
    int wid = t >> 6, lane = t & 63;
    if (lane == 0){ red[wid] = s; red[4 + wid] = sq; }
    __syncthreads();
    float S  = red[0] + red[1] + red[2] + red[3];
    float SQ = red[4] + red[5] + red[6] + red[7];
    float mean = S * (1.f/1024.f);
    float var  = SQ * (1.f/1024.f) - mean*mean;     // jnp.var: biased
    float rstd = rsqrtf(var + 1e-5f);
    float4 gv = ((const float4*)g)[t];
    float4 bv = ((const float4*)beta)[t];
    bf16x4 o;
    o[0] = (bf16)((xv.x - mean) * rstd * gv.x + bv.x);
    o[1] = (bf16)((xv.y - mean) * rstd * gv.y + bv.y);
    o[2] = (bf16)((xv.z - mean) * rstd * gv.z + bv.z);
    o[3] = (bf16)((xv.w - mean) * rstd * gv.w + bv.w);
    *(bf16x4*)(out + (size_t)rw * 1024 + t*4) = o;
}

// ---------------- 256x256 bf16 GEMM, register-pipelined 2-barrier ----------
// K-loop is the ROUND-6 VERIFIED schedule, byte-identical.
// NEW: LDS-transpose epilogue. Old epilogue: 128 scalar stores/thread in 32B
// segments (+128 scalar res loads for EPI>=2) — uncoalescible since a lane's
// cols are nt*16+qoff (stride 16). Now: per mt-slice, waves write acc
// (bias/GELU applied) to a padded [32][260] fp32 LDS tile (2-way banks only,
// free), barrier, then threads read row-contiguous float4 and issue coalesced
// dwordx4/dwordx2 stores + float4 res loads. LDS is dead after the K-loop, so
// the tile reuses it; each round is fenced by barriers.
template<int EPI>
__global__ __launch_bounds__(512, 2) void gemm256(
    const bf16* __restrict__ Ag, const bf16* __restrict__ BT,
    const float* __restrict__ bias, const float* __restrict__ res,
    void* __restrict__ outp, int N, int K)
{
    extern __shared__ char lds[];
    const int KT = K >> 6;
    const int gx = N >> 8;
    int nwg = gridDim.x;
    int id  = blockIdx.x;
    int cpx = nwg >> 3;                       // nwg % 8 == 0 for all our calls
    int wg  = (id & 7) * cpx + (id >> 3);     // XCD-aware swizzle (T1)
    int bx = wg % gx, by = wg / gx;
    int m0 = by << 8, n0 = bx << 8;

    int t = threadIdx.x;
    int lane = t & 63, wid = t >> 6;
    int wm = wid >> 2, wn = wid & 3;          // 2 x 4 wave grid
    int qoff = lane & 15, quad = lane >> 4;

    auto stage = [&](int kt, int h){          // h: 0=B-lo 1=B-hi 2=A-lo 3=A-hi
        int isA = h >> 1, hh = h & 1;
        char* lb = lds + ((kt & 1) << 16) + (isA << 15) + (hh << 14);
        const bf16* g0 = (isA ? Ag + (size_t)(m0 + (hh << 7)) * K
                              : BT + (size_t)(n0 + (hh << 7)) * K) + (kt << 6);
        #pragma unroll
        for (int ld = 0; ld < 2; ld++){
            int ch  = ld*512 + t;
            int row = ch >> 3;
            int cc  = (ch & 7) ^ (row & 7);   // pre-swizzled global source
            gload16(g0 + (size_t)row * K + cc*8, lb + (ld*512 + wid*64)*16);
        }
    };

    f32x4 acc[8][4] = {};
    bf16x8 a0[8], a1[8], b0[4], b1[4];

    const char* lA0 = lds + 32768 + (wm << 14) + qoff*128;
    const char* lB0 = lds + ((wn >> 1) << 14) + ((wn & 1) << 13) + qoff*128;
    int p0 = (quad ^ (qoff & 7)) << 4;
    int p1 = p0 ^ 64;

    // prologue: stage tiles 0 and 1 fully; read tile0 a0/b0/b1
    for (int kt = 0; kt < 2; ++kt)
        for (int h = 0; h < 4; ++h) stage(kt, h);
    asm volatile("s_waitcnt vmcnt(8)" ::: "memory");   // tile 0 staged (drain-then-barrier)
    __builtin_amdgcn_s_barrier();
    #pragma unroll
    for (int mt = 0; mt < 8; mt++) a0[mt] = *(const bf16x8*)(lA0 + mt*2048 + p0);
    #pragma unroll
    for (int nt = 0; nt < 4; nt++){
        b0[nt] = *(const bf16x8*)(lB0 + nt*2048 + p0);
        b1[nt] = *(const bf16x8*)(lB0 + nt*2048 + p1);
    }
    asm volatile("s_waitcnt lgkmcnt(0)" ::: "memory"); // drain before B-lo restage
    __builtin_amdgcn_s_barrier();

    for (int j = 0; j < KT; ++j){
        int cur = (j & 1) << 16;
        int nxt = cur ^ 0x10000;
        const char* lA  = lA0 + cur;
        const char* lAn = lA0 + nxt;
        const char* lBn = lB0 + nxt;
        bool sg = (j + 2 < KT);
        bool rd = (j + 1 < KT);

        // ---- H0: stage B-lo/B-hi(j+2); read a1(j); MFMA a0 x b0; gate; barrier
        if (sg) stage(j+2, 0);
        #pragma unroll
        for (int mt = 0; mt < 8; mt++)
            a1[mt] = *(const bf16x8*)(lA + mt*2048 + p1);
        __builtin_amdgcn_sched_barrier(0);
        __builtin_amdgcn_s_setprio(1);
        #pragma unroll
        for (int mt = 0; mt < 8; mt++){
            acc[mt][0] = MFMA(a0[mt], b0[0], acc[mt][0]);
            acc[mt][1] = MFMA(a0[mt], b0[1], acc[mt][1]);
        }
        __builtin_amdgcn_s_setprio(0);
        __builtin_amdgcn_sched_barrier(0);
        if (sg) stage(j+2, 1);
        __builtin_amdgcn_sched_barrier(0);
        __builtin_amdgcn_s_setprio(1);
        #pragma unroll
        for (int mt = 0; mt < 8; mt++){
            acc[mt][2] = MFMA(a0[mt], b0[2], acc[mt][2]);
            acc[mt][3] = MFMA(a0[mt], b0[3], acc[mt][3]);
        }
        __builtin_amdgcn_s_setprio(0);
        __builtin_amdgcn_sched_barrier(0);
        if (sg) asm volatile("s_waitcnt lgkmcnt(0) vmcnt(4)" ::: "memory");
        else    asm volatile("s_waitcnt lgkmcnt(0) vmcnt(0)" ::: "memory");
        __builtin_amdgcn_sched_barrier(0);
        __builtin_amdgcn_s_barrier();

        // ---- H1: stage A-lo/A-hi(j+2); read a0(j+1); MFMA a1 x b1;
        //          read b(j+1) AFTER b1's last use; drain; barrier
        if (sg) stage(j+2, 2);
        if (rd){
            #pragma unroll
            for (int mt = 0; mt < 8; mt++)
                a0[mt] = *(const bf16x8*)(lAn + mt*2048 + p0);
        }
        __builtin_amdgcn_sched_barrier(0);
        __builtin_amdgcn_s_setprio(1);
        #pragma unroll
        for (int mt = 0; mt < 8; mt++){
            acc[mt][0] = MFMA(a1[mt], b1[0], acc[mt][0]);
            acc[mt][1] = MFMA(a1[mt], b1[1], acc[mt][1]);
        }
        __builtin_amdgcn_s_setprio(0);
        __builtin_amdgcn_sched_barrier(0);
        if (sg) stage(j+2, 3);
        __builtin_amdgcn_sched_barrier(0);
        __builtin_amdgcn_s_setprio(1);
        #pragma unroll
        for (int mt = 0; mt < 8; mt++){
            acc[mt][2] = MFMA(a1[mt], b1[2], acc[mt][2]);
            acc[mt][3] = MFMA(a1[mt], b1[3], acc[mt][3]);
        }
        __builtin_amdgcn_s_setprio(0);
        __builtin_amdgcn_sched_barrier(0);
        if (rd){
            #pragma unroll
            for (int nt = 0; nt < 4; nt++){
                b0[nt] = *(const bf16x8*)(lBn + nt*2048 + p0);
                b1[nt] = *(const bf16x8*)(lBn + nt*2048 + p1);
            }
            asm volatile("s_waitcnt lgkmcnt(0)" ::: "memory");
        }
        __builtin_amdgcn_s_barrier();
    }

    // ---- LDS-transpose epilogue -------------------------------------------
    // C/D layout: col = lane&15, row = quad*4+reg  [m91-verified]
    // Per mt: LDS tile [32][260] fp32; lr = wm*16 + quad*4 + reg;
    // global row = m0 + (lr>>4)*128 + mt*16 + (lr&15).
    float* eL = (float*)lds;                       // 32*260*4 = 33.3 KB
    float bias4[4];
    #pragma unroll
    for (int nt = 0; nt < 4; nt++)
        bias4[nt] = bias[n0 + wn*64 + nt*16 + qoff];
    int lrS = t >> 4;                               // store-stage row 0..31
    int cq  = t & 15;

    #pragma unroll
    for (int mt = 0; mt < 8; mt++){
        __syncthreads();                            // prev round's reads done
        #pragma unroll
        for (int reg = 0; reg < 4; reg++){
            int lr = wm*16 + quad*4 + reg;
            #pragma unroll
            for (int nt = 0; nt < 4; nt++){
                float vv = acc[mt][nt][reg] + bias4[nt];
                if (EPI == 1) vv = gelu_exact(vv);
                eL[lr*260 + wn*64 + nt*16 + qoff] = vv;
            }
        }
        __syncthreads();
        int grow = m0 + (lrS >> 4)*128 + mt*16 + (lrS & 15);
        size_t orow = (size_t)grow;
        if (EPI == 2){
            int w = grow >> 8, p = grow & 255;
            int b = w >> 4, inh = (w >> 2) & 3, inw = w & 3, pi = p >> 4, pj = p & 15;
            orow = (size_t)b * 4096 + (inh*16 + pi) * 64 + inw*16 + pj;
        }
        #pragma unroll
        for (int i = 0; i < 4; i++){
            int gc0 = 4*cq + 64*i;                  // col within 256-wide tile
            float4 v4 = *(float4*)&eL[lrS*260 + gc0];
            size_t gidx = orow * (size_t)N + n0 + gc0;
            if (EPI >= 2){
                float4 r4 = *(const float4*)&res[gidx];
                v4.x += r4.x; v4.y += r4.y; v4.z += r4.z; v4.w += r4.w;
                *(float4*)&((float*)outp)[gidx] = v4;
            } else {
                bf16x4 o4;
                o4[0] = (bf16)v4.x; o4[1] = (bf16)v4.y;
                o4[2] = (bf16)v4.z; o4[3] = (bf16)v4.w;
                *(bf16x4*)&((bf16*)outp)[gidx] = o4;
            }
        }
    }
}

// ---------------- windowed attention: 1 block per (window, head) -----------
// fused qkv layout: [32768 rows = win*256+pos][3072 = part*1024 + head*64+d]
__global__ __launch_bounds__(256) void attn_kernel(
    const bf16* __restrict__ qkv, bf16* __restrict__ ao)
{
    __shared__ bf16 VT[64 * 264];      // V^T: [d][kk], stride 264 (16B-aligned)
    __shared__ bf16 Pw[4][16 * 136];   // per-wave P scratch, stride 136
    int wh = blockIdx.x;
    int win = wh >> 4, head = wh & 15;
    size_t base = (size_t)win * 256;
    int cb = head * 64;
    int t = threadIdx.x, lane = t & 63, wv = t >> 6;
    int qoff = lane & 15, quad = lane >> 4;

    // stage V transposed
    const bf16* vb = qkv + base * 3072 + 2048 + cb;
    for (int i = 0; i < 8; i++){
        int c = t + i*256;
        int row = c >> 3, d0 = (c & 7) * 8;
        bf16x8 vvec = *(const bf16x8*)&vb[(size_t)row * 3072 + d0];
        for (int j = 0; j < 8; j++) VT[(d0 + j) * 264 + row] = vvec[j];
    }
    __syncthreads();

    const bf16* qb = qkv + base * 3072 + cb;
    const bf16* kb = qkv + base * 3072 + 1024 + cb;

    for (int qblk = 0; qblk < 4; qblk++){
        int m0 = wv * 64 + qblk * 16;
        bf16x8 aq0 = *(const bf16x8*)&qb[(size_t)(m0 + qoff) * 3072 + quad*8];
        bf16x8 aq1 = *(const bf16x8*)&qb[(size_t)(m0 + qoff) * 3072 + 32 + quad*8];
        f32x4 S[16];
        __builtin_amdgcn_s_setprio(1);
        for (int nt = 0; nt < 16; nt++){
            bf16x8 b0 = *(const bf16x8*)&kb[(size_t)(nt*16 + qoff) * 3072 + quad*8];
            bf16x8 b1 = *(const bf16x8*)&kb[(size_t)(nt*16 + qoff) * 3072 + 32 + quad*8];
            f32x4 a = {0.f, 0.f, 0.f, 0.f};
            a = MFMA(aq0, b0, a);
            a = MFMA(aq1, b1, a);
            S[nt] = a;
        }
        __builtin_amdgcn_s_setprio(0);
        // softmax over 256 keys; row = quad*4+reg, cols nt*16+qoff across 16 lanes
        float inv[4];
        for (int r = 0; r < 4; r++){
            float mx = -1e30f;
            for (int nt = 0; nt < 16; nt++) mx = fmaxf(mx, S[nt][r]);
            for (int m = 1; m < 16; m <<= 1) mx = fmaxf(mx, __shfl_xor(mx, m));
            float sum = 0.f;
            for (int nt = 0; nt < 16; nt++){
                float p = __expf((S[nt][r] - mx) * 0.125f);  // SCALE = 1/8
                S[nt][r] = p; sum += p;
            }
            for (int m = 1; m < 16; m <<= 1) sum += __shfl_xor(sum, m);
            inv[r] = 1.f / sum;
        }
        // PV in two k-halves through per-wave LDS (C-layout -> A-layout)
        f32x4 O[4] = {};
        for (int h = 0; h < 2; h++){
            for (int nt = 0; nt < 8; nt++)
                for (int r = 0; r < 4; r++)
                    Pw[wv][(quad*4 + r)*136 + nt*16 + qoff] = (bf16)S[h*8 + nt][r];
            __builtin_amdgcn_s_setprio(1);
            for (int ks = 0; ks < 4; ks++){
                bf16x8 ap = *(bf16x8*)&Pw[wv][qoff*136 + ks*32 + quad*8];
                for (int vt = 0; vt < 4; vt++){
                    bf16x8 bvv = *(bf16x8*)&VT[(vt*16 + qoff)*264 + (h*4 + ks)*32 + quad*8];
                    O[vt] = MFMA(ap, bvv, O[vt]);
                }
            }
            __builtin_amdgcn_s_setprio(0);
        }
        for (int vt = 0; vt < 4; vt++)
            for (int r = 0; r < 4; r++){
                size_t row = base + m0 + quad*4 + r;
                ao[row * 1024 + cb + vt*16 + qoff] = (bf16)(O[vt][r] * inv[r]);
            }
    }
}

// ---------------- orchestration -------------------------------------------
extern "C" void kernel_launch(void* const* d_in, const int* in_sizes, int n_in,
                              void* d_out, int out_size, void* d_ws, size_t ws_size,
                              hipStream_t stream)
{
    const float* x     = (const float*)d_in[0];
    const float* g1    = (const float*)d_in[1];
    const float* beta1 = (const float*)d_in[2];
    const float* Wq    = (const float*)d_in[3];
    const float* bq    = (const float*)d_in[4];
    const float* Wk    = (const float*)d_in[5];
    const float* bk    = (const float*)d_in[6];
    const float* Wv    = (const float*)d_in[7];
    const float* bv    = (const float*)d_in[8];
    const float* Wo    = (const float*)d_in[9];
    const float* bo    = (const float*)d_in[10];
    const float* g2    = (const float*)d_in[11];
    const float* beta2 = (const float*)d_in[12];
    const float* W1    = (const float*)d_in[13];
    const float* b1m   = (const float*)d_in[14];
    const float* W2    = (const float*)d_in[15];
    const float* b2m   = (const float*)d_in[16];

    char* ws = (char*)d_ws;
    const size_t MB = 1024ull * 1024ull;
    bf16* WqkvT = (bf16*)(ws + 0*MB);    // 6 MB  [3072][1024]
    bf16* WoT   = (bf16*)(ws + 6*MB);    // 2 MB
    bf16* W1T   = (bf16*)(ws + 8*MB);    // 8 MB  [4096][1024]
    bf16* W2T   = (bf16*)(ws + 16*MB);   // 8 MB  [1024][4096]
    bf16* hw    = (bf16*)(ws + 24*MB);   // 64 MB  (window-layout LN1 out)
    bf16* qkv   = (bf16*)(ws + 88*MB);   // 192 MB (fused q|k|v, stride 3072)
    bf16* ao    = (bf16*)(ws + 24*MB);   // reuse hw (consumed by QKV gemm)
    bf16* m1    = (bf16*)(ws + 24*MB);   // 256 MB overlay (hw+qkv, both dead)
    float* x2   = (float*)(ws + 280*MB); // 128 MB
    float* bqkv = (float*)(ws + 280*MB); // 12 KB, overlays x2 (dead until O-proj)
    bf16* h2    = (bf16*)(ws + 408*MB);  // 64 MB   -> total 472 MB

    static bool s_attr = false;
    if (!s_attr){
        s_attr = true;
        hipFuncSetAttribute(reinterpret_cast<const void*>(gemm256<0>),
                            hipFuncAttributeMaxDynamicSharedMemorySize, 131072);
        hipFuncSetAttribute(reinterpret_cast<const void*>(gemm256<1>),
                            hipFuncAttributeMaxDynamicSharedMemorySize, 131072);
        hipFuncSetAttribute(reinterpret_cast<const void*>(gemm256<2>),
                            hipFuncAttributeMaxDynamicSharedMemorySize, 131072);
        hipFuncSetAttribute(reinterpret_cast<const void*>(gemm256<3>),
                            hipFuncAttributeMaxDynamicSharedMemorySize, 131072);
    }

    dim3 tb(32, 8);

    // weight prep (Wq/Wk/Wv concatenated row-wise into WqkvT)
    wprep<<<dim3(32, 32),  tb, 0, stream>>>(Wq, WqkvT,              1024, 1024);
    wprep<<<dim3(32, 32),  tb, 0, stream>>>(Wk, WqkvT + 1024*1024,  1024, 1024);
    wprep<<<dim3(32, 32),  tb, 0, stream>>>(Wv, WqkvT + 2048*1024,  1024, 1024);
    wprep<<<dim3(32, 32),  tb, 0, stream>>>(Wo, WoT, 1024, 1024);
    wprep<<<dim3(128, 32), tb, 0, stream>>>(W1, W1T, 1024, 4096);
    wprep<<<dim3(32, 128), tb, 0, stream>>>(W2, W2T, 4096, 1024);
    bcat<<<12, 256, 0, stream>>>(bq, bk, bv, bqkv);

    // LN1 + window partition
    ln_kernel<1><<<32768, 256, 0, stream>>>(x, g1, beta1, hw);

    // fused QKV projection: [32768,1024] x [1024,3072]
    gemm256<0><<<12*128, 512, 131072, stream>>>(hw, WqkvT, bqkv, nullptr, qkv, 3072, 1024);

    // windowed attention (128 windows x 16 heads)
    attn_kernel<<<2048, 256, 0, stream>>>(qkv, ao);

    // O projection + bias + residual + window un-partition -> x2 (fp32)
    gemm256<2><<<4*128, 512, 131072, stream>>>(ao, WoT, bo, x, x2, 1024, 1024);

    // LN2
    ln_kernel<0><<<32768, 256, 0, stream>>>(x2, g2, beta2, h2);

    // MLP
    gemm256<1><<<16*128, 512, 131072, stream>>>(h2, W1T, b1m, nullptr, m1, 4096, 1024);
    gemm256<3><<<4*128, 512, 131072, stream>>>(m1, W2T, b2m, x2, (float*)d_out, 1024, 4096);
}